// Round 1
// 530.097 us; speedup vs baseline: 1.0359x; 1.0359x over previous
//
#include <hip/hip_runtime.h>
#include <hip/hip_fp16.h>
#include <cstdint>
#include <cstddef>

#define N_NODES 100000
#define N_EDGES 1600000
#define D 128
#define NLAYERS 3
#define NB 3125       // buckets of 32 nodes
#define NBLK_E 128    // edge-phase blocks
#define EPB 12500     // edges per block: 1600000/128
#define ENT_CAP 1024  // fill2 LDS entries; bucket max ~600 (22 sigma)

typedef float f2v __attribute__((ext_vector_type(2)));
typedef float f4v __attribute__((ext_vector_type(4)));

// ---------------- CSR build: LDS-histogram counting sort (no global atomics) ----------------

__global__ __launch_bounds__(512) void hist1_kernel(const int* __restrict__ col,
                                                    int* __restrict__ hmat) {
    __shared__ int hist[NB];
    int b = blockIdx.x, t = threadIdx.x;
    for (int j = t; j < NB; j += 512) hist[j] = 0;
    __syncthreads();
    int base = b * EPB;
    for (int i = t; i < EPB; i += 512) {
        int c = col[base + i];
        atomicAdd(&hist[c >> 5], 1);  // LDS atomic
    }
    __syncthreads();
    for (int j = t; j < NB; j += 512) hmat[b * NB + j] = hist[j];
}

__global__ void btot_kernel(const int* __restrict__ hmat, int* __restrict__ btot) {
    int j = blockIdx.x * 256 + threadIdx.x;
    if (j < NB) {
        int s = 0;
        for (int b = 0; b < NBLK_E; b++) s += hmat[b * NB + j];
        btot[j] = s;
    }
}

// Single-block exclusive scan over 3125 bucket totals -> bstart (+ sentinel).
__global__ void bscan_kernel(const int* __restrict__ btot, int* __restrict__ bstart, int nb, int e) {
    __shared__ int lsum[1024];
    int t = threadIdx.x;
    int vals[4];
    int v0 = 0;
#pragma unroll
    for (int j = 0; j < 4; j++) {
        int idx = t * 4 + j;
        int c = (idx < nb) ? btot[idx] : 0;
        vals[j] = c;
        v0 += c;
    }
    lsum[t] = v0;
    __syncthreads();
    for (int off = 1; off < 1024; off <<= 1) {
        int x = (t >= off) ? lsum[t - off] : 0;
        __syncthreads();
        lsum[t] += x;
        __syncthreads();
    }
    int base = lsum[t] - v0;  // exclusive
#pragma unroll
    for (int j = 0; j < 4; j++) {
        int idx = t * 4 + j;
        if (idx < nb) {
            bstart[idx] = base;
            base += vals[j];
        }
    }
    if (t == 0) bstart[nb] = e;
}

// Per-(block,bucket) start offsets: hoff[b][j] = bstart[j] + sum_{b'<b} hmat[b'][j]
__global__ void hoff_kernel(const int* __restrict__ hmat, const int* __restrict__ bstart,
                            int* __restrict__ hoff) {
    int j = blockIdx.x * 256 + threadIdx.x;
    if (j < NB) {
        int run = bstart[j];
        for (int b = 0; b < NBLK_E; b++) {
            hoff[b * NB + j] = run;
            run += hmat[b * NB + j];
        }
    }
}

// Scatter edges to exact bucket-sorted positions. LDS cursors, no global atomics.
__global__ __launch_bounds__(512) void scatter_kernel(const int* __restrict__ row,
                                                      const int* __restrict__ col,
                                                      const int* __restrict__ hoff,
                                                      unsigned* __restrict__ bucketbuf) {
    __shared__ int cur[NB];
    int b = blockIdx.x, t = threadIdx.x;
    for (int j = t; j < NB; j += 512) cur[j] = hoff[b * NB + j];
    __syncthreads();
    int base = b * EPB;
    for (int i = t; i < EPB; i += 512) {
        int r = row[base + i], c = col[base + i];
        int pos = atomicAdd(&cur[c >> 5], 1);  // LDS atomic
        bucketbuf[pos] = ((unsigned)r << 5) | (unsigned)(c & 31);
    }
}

// One block per bucket: LDS histogram of 32 local cols -> per-node offsets,
// dinv, and localized CSR scatter (contiguous ~2KB range, LDS cursors).
__global__ void fill2_kernel(const unsigned* __restrict__ bucketbuf, const int* __restrict__ bstart,
                             int* __restrict__ offsets, float* __restrict__ dinv,
                             int* __restrict__ src, int n, int e) {
    __shared__ unsigned ent[ENT_CAP];
    __shared__ int hist[32];
    __shared__ int cur[32];
    __shared__ int loff[32];
    int b = blockIdx.x, t = threadIdx.x;
    int s0 = bstart[b];
    int cnt = bstart[b + 1] - s0;
    if (cnt > ENT_CAP) cnt = ENT_CAP;
    if (t < 32) hist[t] = 0;
    __syncthreads();
    for (int i = t; i < cnt; i += 256) {
        unsigned v = bucketbuf[s0 + i];
        ent[i] = v;
        atomicAdd(&hist[v & 31], 1);
    }
    __syncthreads();
    if (t == 0) {
        int run = s0;
#pragma unroll
        for (int j = 0; j < 32; j++) {
            loff[j] = run;
            run += hist[j];
        }
    }
    __syncthreads();
    if (t < 32) {
        int node = b * 32 + t;
        int o = loff[t];
        offsets[node] = o;
        cur[t] = o;
        dinv[node] = rsqrtf((float)(hist[t] + 1));  // +1 self loop
    }
    if (b == 0 && t == 0) offsets[n] = e;
    __syncthreads();
    for (int i = t; i < cnt; i += 256) {
        unsigned v = ent[i];
        int pos = atomicAdd(&cur[v & 31], 1);
        src[pos] = (int)(v >> 5);
    }
}

// ---------------- per-layer kernels ----------------

// Cast + pre-scale: xs[v] = fp16(dinv[v] * emb[v]). Pre-scaling removes the
// per-edge dinv[src] gather + multiply from the agg inner loop.
__global__ void cast_kernel(const float2* __restrict__ in, const float* __restrict__ dinv,
                            __half2* __restrict__ out, int n2) {
    int i = blockIdx.x * 256 + threadIdx.x;
    if (i < n2) {
        float d = dinv[i >> 6];  // wave-uniform (64 half2 per node)
        float2 v = in[i];
        out[i] = __floats2half2_rn(d * v.x, d * v.y);
    }
}

// One 64-thread block (=1 wave) per node; each thread owns a half2 pair.
// xs is PRE-SCALED: xs[v] = dinv[v]*x[v]. So:
//   out[v] = dinv[v] * ( xs[v] + sum_e xs[src_e] ), fp32 accum.
// 8-wide unroll keeps 8 x 256B gathers in flight per wave (was 4) and the
// chain is now just src -> gather -> add (dinv gather removed).
// Output stored nontemporal: the 50MB write stream must not evict xs rows
// from the 4MB/XCD L2 (they are the gather working set).
__global__ void agg_kernel(const __half2* __restrict__ xs, const int* __restrict__ offs,
                           float* __restrict__ out, const float* __restrict__ dinv,
                           const int* __restrict__ src) {
    int v = blockIdx.x;
    int f = threadIdx.x;  // 0..63
    float dv = dinv[v];
    float2 a0 = __half22float2(xs[(size_t)v * 64 + f]);  // self term (already scaled)
    float ax = a0.x;
    float ay = a0.y;
    int i = offs[v], s1 = offs[v + 1];
    // full 8-groups
    for (; i + 7 < s1; i += 8) {
        int s[8];
#pragma unroll
        for (int j = 0; j < 8; j++) s[j] = src[i + j];
        float2 x[8];
#pragma unroll
        for (int j = 0; j < 8; j++) x[j] = __half22float2(xs[(size_t)s[j] * 64 + f]);
#pragma unroll
        for (int j = 0; j < 8; j++) {
            ax += x[j].x;
            ay += x[j].y;
        }
    }
    // masked tail group (clamped index re-gathers a cached row; contribution zeroed)
    if (i < s1) {
        int last = s1 - 1;
        int s[8];
        float m[8];
#pragma unroll
        for (int j = 0; j < 8; j++) {
            int idx = i + j;
            bool in = idx < s1;
            s[j] = src[in ? idx : last];
            m[j] = in ? 1.0f : 0.0f;
        }
        float2 x[8];
#pragma unroll
        for (int j = 0; j < 8; j++) x[j] = __half22float2(xs[(size_t)s[j] * 64 + f]);
#pragma unroll
        for (int j = 0; j < 8; j++) {
            ax += m[j] * x[j].x;
            ay += m[j] * x[j].y;
        }
    }
    f2v r;
    r.x = dv * ax;
    r.y = dv * ay;
    __builtin_nontemporal_store(r, (f2v*)out + (size_t)v * 64 + f);
}

// out[M x 128] = relu(A[M x 128] @ W[128 x 128] + bias), 32 rows per block,
// W staged in LDS (64 KB), k-vectorized float4 inner loop.
// A is a read-once stream -> nontemporal loads (don't evict W / fresh xs).
// fp32 'out' is only needed at the LAST layer (write_out); intermediate
// layers only need the pre-scaled fp16 copy (write_h) -> saves 2x51.2MB writes.
__global__ __launch_bounds__(256, 2) void gemm_bias_relu_kernel(
    const float* __restrict__ A, const float* __restrict__ W,
    const float* __restrict__ bias, float* __restrict__ out,
    __half2* __restrict__ xs_out, const float* __restrict__ dinv,
    int write_h, int write_out) {
    __shared__ float sW[128 * 128];  // 64 KB
    __shared__ float sX[32 * 128];   // 16 KB
    int t = threadIdx.x;
    int tx = t & 31;   // 32 col-groups of 4
    int ty = t >> 5;   // 8 row-groups of 4
    int row0 = blockIdx.x * 32;

    const f4v* W4 = (const f4v*)W;
    f4v* sW4 = (f4v*)sW;
#pragma unroll
    for (int i = 0; i < 16; i++) sW4[t + 256 * i] = W4[t + 256 * i];

    const f4v* A4 = (const f4v*)A;
    f4v* sX4 = (f4v*)sX;
#pragma unroll
    for (int i = 0; i < 4; i++) {
        int c = t + 256 * i;
        int r = c >> 5, kc = c & 31;
        sX4[r * 32 + kc] = __builtin_nontemporal_load(&A4[(size_t)(row0 + r) * 32 + kc]);
    }
    __syncthreads();

    float4 acc[4];
#pragma unroll
    for (int r = 0; r < 4; r++) acc[r] = make_float4(0.f, 0.f, 0.f, 0.f);

#define FMA4(a, s, b) a.x += (s) * (b).x; a.y += (s) * (b).y; a.z += (s) * (b).z; a.w += (s) * (b).w;
#pragma unroll 4
    for (int k0 = 0; k0 < 128; k0 += 4) {
        float4 b0 = *(const float4*)&sW[(k0 + 0) * 128 + tx * 4];
        float4 b1 = *(const float4*)&sW[(k0 + 1) * 128 + tx * 4];
        float4 b2 = *(const float4*)&sW[(k0 + 2) * 128 + tx * 4];
        float4 b3 = *(const float4*)&sW[(k0 + 3) * 128 + tx * 4];
#pragma unroll
        for (int r = 0; r < 4; r++) {
            float4 a = *(const float4*)&sX[(ty * 4 + r) * 128 + k0];
            FMA4(acc[r], a.x, b0)
            FMA4(acc[r], a.y, b1)
            FMA4(acc[r], a.z, b2)
            FMA4(acc[r], a.w, b3)
        }
    }
#undef FMA4

    float4 bb = ((const float4*)bias)[tx];
#pragma unroll
    for (int r = 0; r < 4; r++) {
        float4 o;
        o.x = fmaxf(acc[r].x + bb.x, 0.0f);
        o.y = fmaxf(acc[r].y + bb.y, 0.0f);
        o.z = fmaxf(acc[r].z + bb.z, 0.0f);
        o.w = fmaxf(acc[r].w + bb.w, 0.0f);
        size_t rowi = (size_t)(row0 + ty * 4 + r);
        if (write_out) {
            f4v ov;
            ov.x = o.x; ov.y = o.y; ov.z = o.z; ov.w = o.w;
            __builtin_nontemporal_store(ov, (f4v*)out + rowi * 32 + tx);
        }
        if (write_h) {
            float dr = dinv[rowi];
            xs_out[rowi * 64 + tx * 2] = __floats2half2_rn(dr * o.x, dr * o.y);
            xs_out[rowi * 64 + tx * 2 + 1] = __floats2half2_rn(dr * o.z, dr * o.w);
        }
    }
}

// ---------------- launch ----------------

extern "C" void kernel_launch(void* const* d_in, const int* in_sizes, int n_in,
                              void* d_out, int out_size, void* d_ws, size_t ws_size,
                              hipStream_t stream) {
    const int* edge = (const int*)d_in[0];   // [2, E] int32
    const float* emb = (const float*)d_in[1];
    const float* Ws = (const float*)d_in[2]; // [L, D, D]
    const float* bs = (const float*)d_in[3]; // [L, D]
    float* out = (float*)d_out;

    const int n = N_NODES, e = N_EDGES;
    const int* row = edge;       // sources
    const int* col = edge + e;   // targets

    char* p = (char*)d_ws;
    float* aggbuf = (float*)p;
    int* hmat = (int*)p;                      // aliases aggbuf (dead until first agg)
    int* hoff = hmat + (size_t)NBLK_E * NB;
    p += (size_t)n * D * 4;                   // 51.2 MB
    __half2* xs = (__half2*)p;                // 25.6 MB (pre-scaled fp16 features)
    unsigned* bucketbuf = (unsigned*)p;       // aliases xs: dead before cast runs
    p += (size_t)n * D * 2;
    int* csr_src  = (int*)p;    p += (size_t)e * 4;           // 6.4 MB
    float* dinv   = (float*)p;  p += (size_t)n * 4;
    int* offsets  = (int*)p;    p += (size_t)(n + 1) * 4;
    int* btot     = (int*)p;    p += (size_t)NB * 4;
    int* bstart   = (int*)p;    p += (size_t)(NB + 1) * 4;

    hist1_kernel<<<NBLK_E, 512, 0, stream>>>(col, hmat);
    btot_kernel<<<(NB + 255) / 256, 256, 0, stream>>>(hmat, btot);
    bscan_kernel<<<1, 1024, 0, stream>>>(btot, bstart, NB, e);
    hoff_kernel<<<(NB + 255) / 256, 256, 0, stream>>>(hmat, bstart, hoff);
    scatter_kernel<<<NBLK_E, 512, 0, stream>>>(row, col, hoff, bucketbuf);
    fill2_kernel<<<NB, 256, 0, stream>>>(bucketbuf, bstart, offsets, dinv, csr_src, n, e);

    int n2 = n * 64;  // half2 count
    cast_kernel<<<(n2 + 255) / 256, 256, 0, stream>>>((const float2*)emb, dinv, xs, n2);

    for (int l = 0; l < NLAYERS; l++) {
        agg_kernel<<<n, 64, 0, stream>>>(xs, offsets, aggbuf, dinv, csr_src);
        gemm_bias_relu_kernel<<<n / 32, 256, 0, stream>>>(
            aggbuf, Ws + (size_t)l * D * D, bs + (size_t)l * D, out,
            xs, dinv,
            (l < NLAYERS - 1) ? 1 : 0, (l == NLAYERS - 1) ? 1 : 0);
    }
}

// Round 2
// 525.530 us; speedup vs baseline: 1.0449x; 1.0087x over previous
//
#include <hip/hip_runtime.h>
#include <hip/hip_fp16.h>
#include <cstdint>
#include <cstddef>

#define N_NODES 100000
#define N_PAD 100096      // N rounded up to 128 (gemm row-tile)
#define N_EDGES 1600000
#define D 128
#define NLAYERS 3
#define NB 3125       // buckets of 32 nodes
#define NBLK_E 128    // edge-phase blocks
#define EPB 12500     // edges per block: 1600000/128
#define ENT_CAP 1024  // fill2 LDS entries; bucket max ~600 (22 sigma)

typedef float f2v __attribute__((ext_vector_type(2)));
typedef float f4v __attribute__((ext_vector_type(4)));

// ---------------- CSR build: LDS-histogram counting sort (no global atomics) ----------------

__global__ __launch_bounds__(512) void hist1_kernel(const int* __restrict__ col,
                                                    int* __restrict__ hmat) {
    __shared__ int hist[NB];
    int b = blockIdx.x, t = threadIdx.x;
    for (int j = t; j < NB; j += 512) hist[j] = 0;
    __syncthreads();
    int base = b * EPB;
    for (int i = t; i < EPB; i += 512) {
        int c = col[base + i];
        atomicAdd(&hist[c >> 5], 1);  // LDS atomic
    }
    __syncthreads();
    for (int j = t; j < NB; j += 512) hmat[b * NB + j] = hist[j];
}

__global__ void btot_kernel(const int* __restrict__ hmat, int* __restrict__ btot) {
    int j = blockIdx.x * 256 + threadIdx.x;
    if (j < NB) {
        int s = 0;
        for (int b = 0; b < NBLK_E; b++) s += hmat[b * NB + j];
        btot[j] = s;
    }
}

// Single-block exclusive scan over 3125 bucket totals -> bstart (+ sentinel).
__global__ void bscan_kernel(const int* __restrict__ btot, int* __restrict__ bstart, int nb, int e) {
    __shared__ int lsum[1024];
    int t = threadIdx.x;
    int vals[4];
    int v0 = 0;
#pragma unroll
    for (int j = 0; j < 4; j++) {
        int idx = t * 4 + j;
        int c = (idx < nb) ? btot[idx] : 0;
        vals[j] = c;
        v0 += c;
    }
    lsum[t] = v0;
    __syncthreads();
    for (int off = 1; off < 1024; off <<= 1) {
        int x = (t >= off) ? lsum[t - off] : 0;
        __syncthreads();
        lsum[t] += x;
        __syncthreads();
    }
    int base = lsum[t] - v0;  // exclusive
#pragma unroll
    for (int j = 0; j < 4; j++) {
        int idx = t * 4 + j;
        if (idx < nb) {
            bstart[idx] = base;
            base += vals[j];
        }
    }
    if (t == 0) bstart[nb] = e;
}

// Per-(block,bucket) start offsets: hoff[b][j] = bstart[j] + sum_{b'<b} hmat[b'][j]
__global__ void hoff_kernel(const int* __restrict__ hmat, const int* __restrict__ bstart,
                            int* __restrict__ hoff) {
    int j = blockIdx.x * 256 + threadIdx.x;
    if (j < NB) {
        int run = bstart[j];
        for (int b = 0; b < NBLK_E; b++) {
            hoff[b * NB + j] = run;
            run += hmat[b * NB + j];
        }
    }
}

// Scatter edges to exact bucket-sorted positions. LDS cursors, no global atomics.
__global__ __launch_bounds__(512) void scatter_kernel(const int* __restrict__ row,
                                                      const int* __restrict__ col,
                                                      const int* __restrict__ hoff,
                                                      unsigned* __restrict__ bucketbuf) {
    __shared__ int cur[NB];
    int b = blockIdx.x, t = threadIdx.x;
    for (int j = t; j < NB; j += 512) cur[j] = hoff[b * NB + j];
    __syncthreads();
    int base = b * EPB;
    for (int i = t; i < EPB; i += 512) {
        int r = row[base + i], c = col[base + i];
        int pos = atomicAdd(&cur[c >> 5], 1);  // LDS atomic
        bucketbuf[pos] = ((unsigned)r << 5) | (unsigned)(c & 31);
    }
}

// One block per bucket: LDS histogram of 32 local cols -> per-node offsets,
// dinv, and localized CSR scatter (contiguous ~2KB range, LDS cursors).
__global__ void fill2_kernel(const unsigned* __restrict__ bucketbuf, const int* __restrict__ bstart,
                             int* __restrict__ offsets, float* __restrict__ dinv,
                             int* __restrict__ src, int n, int e) {
    __shared__ unsigned ent[ENT_CAP];
    __shared__ int hist[32];
    __shared__ int cur[32];
    __shared__ int loff[32];
    int b = blockIdx.x, t = threadIdx.x;
    int s0 = bstart[b];
    int cnt = bstart[b + 1] - s0;
    if (cnt > ENT_CAP) cnt = ENT_CAP;
    if (t < 32) hist[t] = 0;
    __syncthreads();
    for (int i = t; i < cnt; i += 256) {
        unsigned v = bucketbuf[s0 + i];
        ent[i] = v;
        atomicAdd(&hist[v & 31], 1);
    }
    __syncthreads();
    if (t == 0) {
        int run = s0;
#pragma unroll
        for (int j = 0; j < 32; j++) {
            loff[j] = run;
            run += hist[j];
        }
    }
    __syncthreads();
    if (t < 32) {
        int node = b * 32 + t;
        int o = loff[t];
        offsets[node] = o;
        cur[t] = o;
        dinv[node] = rsqrtf((float)(hist[t] + 1));  // +1 self loop
    }
    if (b == 0 && t == 0) offsets[n] = e;
    __syncthreads();
    for (int i = t; i < cnt; i += 256) {
        unsigned v = ent[i];
        int pos = atomicAdd(&cur[v & 31], 1);
        src[pos] = (int)(v >> 5);
    }
}

// ---------------- per-layer kernels ----------------

// Cast + pre-scale: xs[v] = fp16(dinv[v] * emb[v]). Pre-scaling removes the
// per-edge dinv[src] gather + multiply from the agg inner loop.
__global__ void cast_kernel(const float2* __restrict__ in, const float* __restrict__ dinv,
                            __half2* __restrict__ out, int n2) {
    int i = blockIdx.x * 256 + threadIdx.x;
    if (i < n2) {
        float d = dinv[i >> 6];  // wave-uniform (64 half2 per node)
        float2 v = in[i];
        out[i] = __floats2half2_rn(d * v.x, d * v.y);
    }
}

// One 64-thread block (=1 wave) per node; each thread owns a half2 pair.
// xs is PRE-SCALED: xs[v] = dinv[v]*x[v]. So:
//   out[v] = dinv[v] * ( xs[v] + sum_e xs[src_e] ), fp32 accum.
// 8-wide unroll keeps 8 x 256B gathers in flight per wave; chain is just
// src -> gather -> add. Output (51.2MB fp32) stored nontemporal so the write
// stream doesn't evict xs rows (the gather working set) from L2.
__global__ void agg_kernel(const __half2* __restrict__ xs, const int* __restrict__ offs,
                           float* __restrict__ out, const float* __restrict__ dinv,
                           const int* __restrict__ src) {
    int v = blockIdx.x;
    int f = threadIdx.x;  // 0..63
    float dv = dinv[v];
    float2 a0 = __half22float2(xs[(size_t)v * 64 + f]);  // self term (already scaled)
    float ax = a0.x;
    float ay = a0.y;
    int i = offs[v], s1 = offs[v + 1];
    // full 8-groups
    for (; i + 7 < s1; i += 8) {
        int s[8];
#pragma unroll
        for (int j = 0; j < 8; j++) s[j] = src[i + j];
        float2 x[8];
#pragma unroll
        for (int j = 0; j < 8; j++) x[j] = __half22float2(xs[(size_t)s[j] * 64 + f]);
#pragma unroll
        for (int j = 0; j < 8; j++) {
            ax += x[j].x;
            ay += x[j].y;
        }
    }
    // masked tail group (clamped index re-gathers a cached row; contribution zeroed)
    if (i < s1) {
        int last = s1 - 1;
        int s[8];
        float m[8];
#pragma unroll
        for (int j = 0; j < 8; j++) {
            int idx = i + j;
            bool in = idx < s1;
            s[j] = src[in ? idx : last];
            m[j] = in ? 1.0f : 0.0f;
        }
        float2 x[8];
#pragma unroll
        for (int j = 0; j < 8; j++) x[j] = __half22float2(xs[(size_t)s[j] * 64 + f]);
#pragma unroll
        for (int j = 0; j < 8; j++) {
            ax += m[j] * x[j].x;
            ay += m[j] * x[j].y;
        }
    }
    f2v r;
    r.x = dv * ax;
    r.y = dv * ay;
    __builtin_nontemporal_store(r, (f2v*)out + (size_t)v * 64 + f);
}

// out[M x 128] = relu(A[M x 128] @ W[128 x 128] + bias).
// Rewritten vs prior round: the 32-row/4x4 version was LDS-instruction-bound
// (2 ds_read_b128 per 16 FMA -> 3x over the per-CU LDS unit -> 64us vs the
// 21us FMA roofline). Now: BM=128, 8x8 outputs per thread, K chunked by 32.
// A staged TRANSPOSED [k][row] (XOR-swizzled rows so both the staging writes
// and per-k reads spread banks), W staged [k][col]. Per k: 4 ds_read_b128
// feed 64 FMAs (A-reads are 4-address broadcasts) -> near FMA-bound.
// All fp32: numerics identical to previous round.
__global__ __launch_bounds__(256) void gemm_bias_relu_kernel(
    const float* __restrict__ A, const float* __restrict__ W,
    const float* __restrict__ bias, float* __restrict__ out,
    __half2* __restrict__ xs_out, const float* __restrict__ dinv,
    int write_h, int write_out, int n) {
    __shared__ float sA[32 * 128];  // [k][row] fp32, 16 KB, row-XOR-swizzled
    __shared__ float sW[32 * 128];  // [k][col] fp32, 16 KB
    int t = threadIdx.x;
    int tx = t & 15;   // col-group: cols tx*8 .. tx*8+7
    int ty = t >> 4;   // row-group: rows ty*8 .. ty*8+7
    int row0 = blockIdx.x * 128;

    f4v acc[8][2];
#pragma unroll
    for (int r = 0; r < 8; r++) {
        acc[r][0] = (f4v){0.f, 0.f, 0.f, 0.f};
        acc[r][1] = (f4v){0.f, 0.f, 0.f, 0.f};
    }

    const f4v* A4 = (const f4v*)A;

    for (int kc = 0; kc < 4; kc++) {
        int kb = kc * 32;
        // ---- stage W chunk (linear copy, conflict-free) ----
        {
            const f4v* Wg = (const f4v*)(W + (size_t)kb * 128);
            f4v* sW4 = (f4v*)sW;
#pragma unroll
            for (int i = 0; i < 4; i++) sW4[t + 256 * i] = Wg[t + 256 * i];
        }
        // ---- stage A chunk transposed: sA[kl][row ^ (kl&24)] = A[row0+row][kb+kl] ----
        // global read coalesced (8 rows x 8 float4-chunks per wave);
        // XOR swizzle spreads the strided b32 writes across banks.
#pragma unroll
        for (int i = 0; i < 4; i++) {
            int idx = t + 256 * i;
            int r = idx >> 3;   // 0..127
            int q = idx & 7;    // float4 index within the 32-k chunk
            f4v v = __builtin_nontemporal_load(&A4[(size_t)(row0 + r) * 32 + kc * 8 + q]);
            int k0 = q * 4;
            sA[(k0 + 0) * 128 + (r ^ ((k0 + 0) & 24))] = v.x;
            sA[(k0 + 1) * 128 + (r ^ ((k0 + 1) & 24))] = v.y;
            sA[(k0 + 2) * 128 + (r ^ ((k0 + 2) & 24))] = v.z;
            sA[(k0 + 3) * 128 + (r ^ ((k0 + 3) & 24))] = v.w;
        }
        __syncthreads();

#pragma unroll 8
        for (int k = 0; k < 32; k++) {
            const float* ap = &sA[k * 128 + ((ty * 8) ^ (k & 24))];
            f4v a0 = *(const f4v*)ap;
            f4v a1 = *(const f4v*)(ap + 4);
            const float* bp = &sW[k * 128 + tx * 8];
            f4v b0 = *(const f4v*)bp;
            f4v b1 = *(const f4v*)(bp + 4);
#pragma unroll
            for (int r = 0; r < 4; r++) {
                acc[r][0] += a0[r] * b0;
                acc[r][1] += a0[r] * b1;
                acc[r + 4][0] += a1[r] * b0;
                acc[r + 4][1] += a1[r] * b1;
            }
        }
        __syncthreads();
    }

    // ---- epilogue: bias + relu, guarded stores (last block is partial) ----
    f4v bb0 = ((const f4v*)bias)[tx * 2];
    f4v bb1 = ((const f4v*)bias)[tx * 2 + 1];
#pragma unroll
    for (int r = 0; r < 8; r++) {
        int rowi = row0 + ty * 8 + r;
        if (rowi >= n) continue;
        f4v o0 = acc[r][0] + bb0;
        f4v o1 = acc[r][1] + bb1;
#pragma unroll
        for (int j = 0; j < 4; j++) {
            o0[j] = fmaxf(o0[j], 0.0f);
            o1[j] = fmaxf(o1[j], 0.0f);
        }
        if (write_out) {
            __builtin_nontemporal_store(o0, (f4v*)out + (size_t)rowi * 32 + tx * 2);
            __builtin_nontemporal_store(o1, (f4v*)out + (size_t)rowi * 32 + tx * 2 + 1);
        }
        if (write_h) {
            float dr = dinv[rowi];
            __half2 h[4];
            h[0] = __floats2half2_rn(dr * o0[0], dr * o0[1]);
            h[1] = __floats2half2_rn(dr * o0[2], dr * o0[3]);
            h[2] = __floats2half2_rn(dr * o1[0], dr * o1[1]);
            h[3] = __floats2half2_rn(dr * o1[2], dr * o1[3]);
            *(uint4*)&xs_out[(size_t)rowi * 64 + tx * 4] = *(uint4*)h;
        }
    }
}

// ---------------- launch ----------------

extern "C" void kernel_launch(void* const* d_in, const int* in_sizes, int n_in,
                              void* d_out, int out_size, void* d_ws, size_t ws_size,
                              hipStream_t stream) {
    const int* edge = (const int*)d_in[0];   // [2, E] int32
    const float* emb = (const float*)d_in[1];
    const float* Ws = (const float*)d_in[2]; // [L, D, D]
    const float* bs = (const float*)d_in[3]; // [L, D]
    float* out = (float*)d_out;

    const int n = N_NODES, e = N_EDGES;
    const int* row = edge;       // sources
    const int* col = edge + e;   // targets

    char* p = (char*)d_ws;
    float* aggbuf = (float*)p;
    int* hmat = (int*)p;                      // aliases aggbuf (dead until first agg)
    int* hoff = hmat + (size_t)NBLK_E * NB;
    p += (size_t)N_PAD * D * 4;               // 51.25 MB (padded to 128-row tiles)
    __half2* xs = (__half2*)p;                // 25.6 MB (pre-scaled fp16 features)
    unsigned* bucketbuf = (unsigned*)p;       // aliases xs: dead before cast runs
    p += (size_t)n * D * 2;
    int* csr_src  = (int*)p;    p += (size_t)e * 4;           // 6.4 MB
    float* dinv   = (float*)p;  p += (size_t)n * 4;
    int* offsets  = (int*)p;    p += (size_t)(n + 1) * 4;
    int* btot     = (int*)p;    p += (size_t)NB * 4;
    int* bstart   = (int*)p;    p += (size_t)(NB + 1) * 4;

    hist1_kernel<<<NBLK_E, 512, 0, stream>>>(col, hmat);
    btot_kernel<<<(NB + 255) / 256, 256, 0, stream>>>(hmat, btot);
    bscan_kernel<<<1, 1024, 0, stream>>>(btot, bstart, NB, e);
    hoff_kernel<<<(NB + 255) / 256, 256, 0, stream>>>(hmat, bstart, hoff);
    scatter_kernel<<<NBLK_E, 512, 0, stream>>>(row, col, hoff, bucketbuf);
    fill2_kernel<<<NB, 256, 0, stream>>>(bucketbuf, bstart, offsets, dinv, csr_src, n, e);

    int n2 = n * 64;  // half2 count
    cast_kernel<<<(n2 + 255) / 256, 256, 0, stream>>>((const float2*)emb, dinv, xs, n2);

    const int ngb = N_PAD / 128;  // 782 row-tiles
    for (int l = 0; l < NLAYERS; l++) {
        agg_kernel<<<n, 64, 0, stream>>>(xs, offsets, aggbuf, dinv, csr_src);
        gemm_bias_relu_kernel<<<ngb, 256, 0, stream>>>(
            aggbuf, Ws + (size_t)l * D * D, bs + (size_t)l * D, out,
            xs, dinv,
            (l < NLAYERS - 1) ? 1 : 0, (l == NLAYERS - 1) ? 1 : 0, n);
    }
}